// Round 2
// baseline (919.305 us; speedup 1.0000x reference)
//
#include <hip/hip_runtime.h>
#include <math.h>

// Problem shape (fixed by the harness): logits [1, T, U, D]
#define TDIM 2000
#define UDIM 32
#define DDIM 4096
#define NDIAG (TDIM + UDIM)   // 2032 anti-diagonals, n in [0, 2031]
#define DEPTH 8               // software-pipeline depth for DP loads

// ---------------------------------------------------------------------------
// Kernel 1: per (t,u) row of D=4096 logits compute log-softmax at d=0 (blank)
// and d=tgt[u] (emit), writing straight into DIAGONALIZED layouts so the DP
// kernel's per-step loads are 32 consecutive floats:
//   blkD [n][u] = blk [n-1-u][u]   (stay path operand at wavefront step n)
//   emitD[n][u] = emit[n-u][u-1]   (emit path operand at wavefront step n)
// Row (t,u) owns the single diagonal slot n = t+u+1 for both.
// ---------------------------------------------------------------------------
__global__ __launch_bounds__(256) void k_rowstats(
    const float* __restrict__ logits, const int* __restrict__ tgt,
    float* __restrict__ blkD, float* __restrict__ emitD)
{
    const int r = blockIdx.x;              // r = t*UDIM + u
    const int t = r >> 5;
    const int u = r & (UDIM - 1);
    const float* row = logits + (size_t)r * DDIM;
    const float4* row4 = reinterpret_cast<const float4*>(row);
    const int tid = threadIdx.x;

    float4 x0 = row4[tid];
    float4 x1 = row4[tid + 256];
    float4 x2 = row4[tid + 512];
    float4 x3 = row4[tid + 768];

    float m = fmaxf(fmaxf(fmaxf(x0.x, x0.y), fmaxf(x0.z, x0.w)),
               fmaxf(fmaxf(fmaxf(x1.x, x1.y), fmaxf(x1.z, x1.w)),
                fmaxf(fmaxf(fmaxf(x2.x, x2.y), fmaxf(x2.z, x2.w)),
                      fmaxf(fmaxf(x3.x, x3.y), fmaxf(x3.z, x3.w)))));
    #pragma unroll
    for (int off = 32; off > 0; off >>= 1)
        m = fmaxf(m, __shfl_xor(m, off));

    __shared__ float redm[4];
    __shared__ float reds[4];
    const int wid = tid >> 6, lane = tid & 63;
    if (lane == 0) redm[wid] = m;
    __syncthreads();
    m = fmaxf(fmaxf(redm[0], redm[1]), fmaxf(redm[2], redm[3]));

    float s = 0.f;
    s += expf(x0.x - m) + expf(x0.y - m) + expf(x0.z - m) + expf(x0.w - m);
    s += expf(x1.x - m) + expf(x1.y - m) + expf(x1.z - m) + expf(x1.w - m);
    s += expf(x2.x - m) + expf(x2.y - m) + expf(x2.z - m) + expf(x2.w - m);
    s += expf(x3.x - m) + expf(x3.y - m) + expf(x3.z - m) + expf(x3.w - m);
    #pragma unroll
    for (int off = 32; off > 0; off >>= 1)
        s += __shfl_xor(s, off);
    if (lane == 0) reds[wid] = s;
    __syncthreads();

    if (tid == 0) {
        float tot = (reds[0] + reds[1]) + (reds[2] + reds[3]);
        float l = logf(tot);
        float b = (x0.x - m) - l;            // log_softmax at d=0 (blank)
        float e = (row[tgt[u]] - m) - l;     // log_softmax at d=tgt[u] (L1-hot)
        const int n = t + u + 1;             // diagonal slot owned by this row
        blkD[n * UDIM + u] = b;
        if (u < UDIM - 1)
            emitD[n * UDIM + u + 1] = e;     // emit col 31 is never consumed
    }
}

// ---------------------------------------------------------------------------
// Kernel 2: anti-diagonal wavefront DP, single wave; lane u computes cell
// (t = n-u, u) at step n. Stay path uses own prev value (alpha[t-1,u]),
// emit path uses lane u-1's prev value (alpha[t,u-1]) via __shfl_up —
// reproducing the reference's sequential rounding and ">=" tie-break exactly.
// (start,total) are packed into one int (s*4096 + tt, both exact) so only
// two values cross lanes per step. Loads are coalesced 32-float diagonal
// rows, software-pipelined DEPTH ahead. Lane tl streams all outputs.
// ---------------------------------------------------------------------------
__global__ __launch_bounds__(64) void k_dp(
    const float* __restrict__ blkD, const float* __restrict__ emitD,
    const int* __restrict__ tlenp, float* __restrict__ out)
{
    const int u  = (int)threadIdx.x;         // lanes 0..63; u<UDIM meaningful
    const int tl = tlenp[0];                 // = 31
    float* out_la = out + 1;
    float* out_st = out + 1 + TDIM;
    float* out_to = out + 1 + 2 * TDIM;

    const int NMAX = NDIAG * UDIM - 1;

    float a = 0.f;           // alpha of this lane's previous cell (t-1, u)
    int   p = 1;             // packed start*4096 + total of that cell
    float bp[DEPTH], ep[DEPTH];

    auto issue = [&](int n, float& b, float& e) {
        int idx = n * UDIM + u;
        idx = min(idx, NMAX);
        b = blkD[idx];
        e = emitD[idx];
    };

    #pragma unroll
    for (int k = 0; k < DEPTH; ++k) issue(k, bp[k], ep[k]);

    // NDIAG = 2032 is divisible by DEPTH = 8
    for (int n0 = 0; n0 < NDIAG; n0 += DEPTH) {
        #pragma unroll
        for (int j = 0; j < DEPTH; ++j) {
            const int n = n0 + j;
            const int t = n - u;

            float aL = __shfl_up(a, 1);
            int   pL = __shfl_up(p, 1);

            float fla = (t >= 1) ? (a + bp[j]) : -INFINITY;  // stay (blank)
            float fd  = aL + ep[j];                          // emit (label)

            issue(n + DEPTH, bp[j], ep[j]);   // prefetch, DP-chain independent

            bool  left = (fla >= fd);         // tie prefers blank (reference)
            float na = left ? fla : fd;
            int   np = (left ? p : pL) + 1;   // total += 1
            if (u == 0) { na = 0.f; np = t * 4096 + 1; }  // alpha[t,0]=0
            a = na; p = np;

            if (u == tl && (unsigned)t < (unsigned)TDIM) {
                float bt = blkD[(n + 1) * UDIM + u];   // blk[t][tl], L1-hot
                float la = a + bt;
                int   st = p >> 12;
                int   tt = p & 4095;
                out_la[t] = la;
                out_st[t] = (float)st;
                out_to[t] = (float)(tt + 1);
                if (t == TDIM - 1) out[0] = la;
            }
        }
    }
}

extern "C" void kernel_launch(void* const* d_in, const int* in_sizes, int n_in,
                              void* d_out, int out_size, void* d_ws, size_t ws_size,
                              hipStream_t stream)
{
    const float* logits      = (const float*)d_in[0];
    const int*   targets     = (const int*)d_in[1];
    const int*   target_lens = (const int*)d_in[3];
    float* out = (float*)d_out;

    // ws layout: blkD[NDIAG*UDIM] | emitD[NDIAG*UDIM]  (~508 KB)
    float* blkD  = (float*)d_ws;
    float* emitD = blkD + NDIAG * UDIM;

    k_rowstats<<<TDIM * UDIM, 256, 0, stream>>>(logits, targets, blkD, emitD);
    k_dp<<<1, 64, 0, stream>>>(blkD, emitD, target_lens, out);
}

// Round 3
// 449.980 us; speedup vs baseline: 2.0430x; 2.0430x over previous
//
#include <hip/hip_runtime.h>
#include <math.h>

// Problem shape (fixed by the harness): logits [1, T, U, D]
#define TDIM 2000
#define UDIM 32
#define DDIM 4096
#define NDIAG (TDIM + UDIM)   // 2032 anti-diagonals; 2032 = 16 * 127
#define DEPTH 16              // software-pipeline depth for DP loads

// ---------------------------------------------------------------------------
// Kernel 1: per (t,u) row of D=4096 logits compute log-softmax at d=0 (blank)
// and d=tgt[u] (emit), writing straight into DIAGONALIZED layouts so the DP
// kernel's per-step loads are 32 consecutive floats:
//   blkD [n][u] = blk [n-1-u][u]   (stay path operand at wavefront step n)
//   emitD[n][u] = emit[n-u][u-1]   (emit path operand at wavefront step n)
// Row (t,u) owns the single diagonal slot n = t+u+1 for both.
// ---------------------------------------------------------------------------
__global__ __launch_bounds__(256) void k_rowstats(
    const float* __restrict__ logits, const int* __restrict__ tgt,
    float* __restrict__ blkD, float* __restrict__ emitD)
{
    const int r = blockIdx.x;              // r = t*UDIM + u
    const int t = r >> 5;
    const int u = r & (UDIM - 1);
    const float* row = logits + (size_t)r * DDIM;
    const float4* row4 = reinterpret_cast<const float4*>(row);
    const int tid = threadIdx.x;

    float4 x0 = row4[tid];
    float4 x1 = row4[tid + 256];
    float4 x2 = row4[tid + 512];
    float4 x3 = row4[tid + 768];

    float m = fmaxf(fmaxf(fmaxf(x0.x, x0.y), fmaxf(x0.z, x0.w)),
               fmaxf(fmaxf(fmaxf(x1.x, x1.y), fmaxf(x1.z, x1.w)),
                fmaxf(fmaxf(fmaxf(x2.x, x2.y), fmaxf(x2.z, x2.w)),
                      fmaxf(fmaxf(x3.x, x3.y), fmaxf(x3.z, x3.w)))));
    #pragma unroll
    for (int off = 32; off > 0; off >>= 1)
        m = fmaxf(m, __shfl_xor(m, off));

    __shared__ float redm[4];
    __shared__ float reds[4];
    const int wid = tid >> 6, lane = tid & 63;
    if (lane == 0) redm[wid] = m;
    __syncthreads();
    m = fmaxf(fmaxf(redm[0], redm[1]), fmaxf(redm[2], redm[3]));

    float s = 0.f;
    s += expf(x0.x - m) + expf(x0.y - m) + expf(x0.z - m) + expf(x0.w - m);
    s += expf(x1.x - m) + expf(x1.y - m) + expf(x1.z - m) + expf(x1.w - m);
    s += expf(x2.x - m) + expf(x2.y - m) + expf(x2.z - m) + expf(x2.w - m);
    s += expf(x3.x - m) + expf(x3.y - m) + expf(x3.z - m) + expf(x3.w - m);
    #pragma unroll
    for (int off = 32; off > 0; off >>= 1)
        s += __shfl_xor(s, off);
    if (lane == 0) reds[wid] = s;
    __syncthreads();

    if (tid == 0) {
        float tot = (reds[0] + reds[1]) + (reds[2] + reds[3]);
        float l = logf(tot);
        float b = (x0.x - m) - l;            // log_softmax at d=0 (blank)
        float e = (row[tgt[u]] - m) - l;     // log_softmax at d=tgt[u] (L1-hot)
        const int n = t + u + 1;             // diagonal slot owned by this row
        blkD[n * UDIM + u] = b;
        if (u < UDIM - 1)
            emitD[n * UDIM + u + 1] = e;     // emit col 31 is never consumed
    }
}

// ---------------------------------------------------------------------------
// Kernel 2: anti-diagonal wavefront DP, single wave; lane u computes cell
// (t = n-u, u) at step n. Stay path uses own prev value (alpha[t-1,u]),
// emit path uses lane u-1's prev value (alpha[t,u-1]) via __shfl_up —
// reproducing the reference's sequential rounding and ">=" tie-break exactly.
// (start,total) are packed into one int (s*4096 + tt, both exact) so only
// two values cross lanes per step.
//
// CRITICAL (round-2 lesson): NO dependent loads inside the loop. The value
// lane tl needs for la (blkD[(n+1)*UDIM+u]) is next step's stay operand and
// is already in the prefetch registers as bp[(j+1)%DEPTH] — reading the
// register costs vmcnt(2*DEPTH-2), keeping the pipeline full, whereas a
// fresh load forced vmcnt(0) per step (full pipeline drain, 785 us).
// ---------------------------------------------------------------------------
__global__ __launch_bounds__(64) void k_dp(
    const float* __restrict__ blkD, const float* __restrict__ emitD,
    const int* __restrict__ tlenp, float* __restrict__ out)
{
    const int u  = (int)threadIdx.x;         // lanes 0..63; u<UDIM meaningful
    const int tl = tlenp[0];                 // = 31
    float* out_la = out + 1;
    float* out_st = out + 1 + TDIM;
    float* out_to = out + 1 + 2 * TDIM;

    const int NMAX = NDIAG * UDIM - 1;

    float a = 0.f;           // alpha of this lane's previous cell (t-1, u)
    int   p = 1;             // packed start*4096 + total of that cell
    float bp[DEPTH], ep[DEPTH];

    auto issue = [&](int n, float& b, float& e) {
        int idx = n * UDIM + u;
        idx = min(idx, NMAX);
        b = blkD[idx];
        e = emitD[idx];
    };

    #pragma unroll
    for (int k = 0; k < DEPTH; ++k) issue(k, bp[k], ep[k]);

    for (int n0 = 0; n0 < NDIAG; n0 += DEPTH) {
        #pragma unroll
        for (int j = 0; j < DEPTH; ++j) {
            const int n = n0 + j;
            const int t = n - u;

            float aL = __shfl_up(a, 1);
            int   pL = __shfl_up(p, 1);

            float fla = (t >= 1) ? (a + bp[j]) : -INFINITY;  // stay (blank)
            float fd  = aL + ep[j];                          // emit (label)

            issue(n + DEPTH, bp[j], ep[j]);   // prefetch, DP-chain independent

            bool  left = (fla >= fd);         // tie prefers blank (reference)
            float na = left ? fla : fd;
            int   np = (left ? p : pL) + 1;   // total += 1
            if (u == 0) { na = 0.f; np = t * 4096 + 1; }  // alpha[t,0]=0
            a = na; p = np;

            if (u == tl && (unsigned)t < (unsigned)TDIM) {
                // bp[(j+1)%DEPTH] holds blkD[(n+1)*UDIM+u] = blk[t][tl]:
                // for j<DEPTH-1 it was prefetched DEPTH steps ago; for
                // j==DEPTH-1, bp[0] was re-issued at j==0 for step n+1.
                float bt = bp[(j + 1) % DEPTH];
                float la = a + bt;
                int   st = p >> 12;
                int   tt = p & 4095;
                out_la[t] = la;
                out_st[t] = (float)st;
                out_to[t] = (float)(tt + 1);
                if (t == TDIM - 1) out[0] = la;
            }
        }
    }
}

extern "C" void kernel_launch(void* const* d_in, const int* in_sizes, int n_in,
                              void* d_out, int out_size, void* d_ws, size_t ws_size,
                              hipStream_t stream)
{
    const float* logits      = (const float*)d_in[0];
    const int*   targets     = (const int*)d_in[1];
    const int*   target_lens = (const int*)d_in[3];
    float* out = (float*)d_out;

    // ws layout: blkD[NDIAG*UDIM] | emitD[NDIAG*UDIM]  (~508 KB)
    float* blkD  = (float*)d_ws;
    float* emitD = blkD + NDIAG * UDIM;

    k_rowstats<<<TDIM * UDIM, 256, 0, stream>>>(logits, targets, blkD, emitD);
    k_dp<<<1, 64, 0, stream>>>(blkD, emitD, target_lens, out);
}

// Round 4
// 394.054 us; speedup vs baseline: 2.3329x; 1.1419x over previous
//
#include <hip/hip_runtime.h>
#include <math.h>

// Problem shape (fixed by the harness): logits [1, T, U, D]
#define TDIM 2000
#define UDIM 32
#define DDIM 4096
#define NDIAG (TDIM + UDIM)   // 2032 anti-diagonals; 2032 = 16 * 127
#define DEPTH 16              // software-pipeline depth for DP loads

// ---------------------------------------------------------------------------
// Kernel 1: per (t,u) row of D=4096 logits compute log-softmax at d=0 (blank)
// and d=tgt[u] (emit), writing straight into a DIAGONALIZED INTERLEAVED
// layout so the DP kernel does ONE dwordx2 load per step:
//   dD[n][u].x = blk [n-1-u][u]   (stay path operand at wavefront step n)
//   dD[n][u].y = emit[n-u][u-1]   (emit path operand at wavefront step n)
// Row (t,u) owns slot (t+u+1, u) for .x and slot (t+u+1, u+1) for .y.
// ---------------------------------------------------------------------------
__global__ __launch_bounds__(256) void k_rowstats(
    const float* __restrict__ logits, const int* __restrict__ tgt,
    float* __restrict__ dD)   // float2 array viewed as float*
{
    const int r = blockIdx.x;              // r = t*UDIM + u
    const int t = r >> 5;
    const int u = r & (UDIM - 1);
    const float* row = logits + (size_t)r * DDIM;
    const float4* row4 = reinterpret_cast<const float4*>(row);
    const int tid = threadIdx.x;

    float4 x0 = row4[tid];
    float4 x1 = row4[tid + 256];
    float4 x2 = row4[tid + 512];
    float4 x3 = row4[tid + 768];

    float m = fmaxf(fmaxf(fmaxf(x0.x, x0.y), fmaxf(x0.z, x0.w)),
               fmaxf(fmaxf(fmaxf(x1.x, x1.y), fmaxf(x1.z, x1.w)),
                fmaxf(fmaxf(fmaxf(x2.x, x2.y), fmaxf(x2.z, x2.w)),
                      fmaxf(fmaxf(x3.x, x3.y), fmaxf(x3.z, x3.w)))));
    #pragma unroll
    for (int off = 32; off > 0; off >>= 1)
        m = fmaxf(m, __shfl_xor(m, off));

    __shared__ float redm[4];
    __shared__ float reds[4];
    const int wid = tid >> 6, lane = tid & 63;
    if (lane == 0) redm[wid] = m;
    __syncthreads();
    m = fmaxf(fmaxf(redm[0], redm[1]), fmaxf(redm[2], redm[3]));

    float s = 0.f;
    s += expf(x0.x - m) + expf(x0.y - m) + expf(x0.z - m) + expf(x0.w - m);
    s += expf(x1.x - m) + expf(x1.y - m) + expf(x1.z - m) + expf(x1.w - m);
    s += expf(x2.x - m) + expf(x2.y - m) + expf(x2.z - m) + expf(x2.w - m);
    s += expf(x3.x - m) + expf(x3.y - m) + expf(x3.z - m) + expf(x3.w - m);
    #pragma unroll
    for (int off = 32; off > 0; off >>= 1)
        s += __shfl_xor(s, off);
    if (lane == 0) reds[wid] = s;
    __syncthreads();

    if (tid == 0) {
        float tot = (reds[0] + reds[1]) + (reds[2] + reds[3]);
        float l = logf(tot);
        float b = (x0.x - m) - l;            // log_softmax at d=0 (blank)
        float e = (row[tgt[u]] - m) - l;     // log_softmax at d=tgt[u] (L1-hot)
        const int n = t + u + 1;             // diagonal slot owned by this row
        dD[(n * UDIM + u) * 2] = b;                      // .x of slot (n, u)
        if (u < UDIM - 1)
            dD[(n * UDIM + u + 1) * 2 + 1] = e;          // .y of slot (n, u+1)
    }
}

// ---------------------------------------------------------------------------
// Kernel 2: anti-diagonal wavefront DP, single wave; lane u computes cell
// (t = n-u, u) at step n. Stay path: own prev value (alpha[t-1,u]); emit
// path: lane u-1's prev value via __shfl_up — reproducing the reference's
// sequential rounding and ">=" tie-break exactly. (start,total) packed into
// one int (s*4096 + tt, both exact).
//
// Round-2 lesson: no dependent loads in the loop (bt comes from the prefetch
// registers). Round-3 lesson: no global STORES in the loop either — they
// share vmcnt with the prefetch loads (5 ops/step x 16-step distance > the
// 63-deep vmcnt window => forced deep drains, 330 cy/step). Outputs go to
// LDS (lgkmcnt domain); one coalesced writeout after the loop.
// ---------------------------------------------------------------------------
__global__ __launch_bounds__(64) void k_dp(
    const float2* __restrict__ dD, const int* __restrict__ tlenp,
    float* __restrict__ out)
{
    const int u  = (int)threadIdx.x;         // lanes 0..63; u<UDIM meaningful
    const int tl = tlenp[0];                 // = 31

    __shared__ float lds_la[TDIM];
    __shared__ int   lds_p[TDIM];

    const int NMAX = NDIAG * UDIM - 1;

    float a = 0.f;           // alpha of this lane's previous cell (t-1, u)
    int   p = 1;             // packed start*4096 + total of that cell
    float2 pre[DEPTH];

    auto issue = [&](int n, float2& d) {
        int idx = n * UDIM + u;
        idx = min(idx, NMAX);
        d = dD[idx];
    };

    #pragma unroll
    for (int k = 0; k < DEPTH; ++k) issue(k, pre[k]);

    for (int n0 = 0; n0 < NDIAG; n0 += DEPTH) {
        #pragma unroll
        for (int j = 0; j < DEPTH; ++j) {
            const int n = n0 + j;
            const int t = n - u;

            float aL = __shfl_up(a, 1);
            int   pL = __shfl_up(p, 1);

            float fla = (t >= 1) ? (a + pre[j].x) : -INFINITY;  // stay (blank)
            float fd  = aL + pre[j].y;                          // emit (label)

            // bt = blkD[(n+1)*UDIM+u] = blk[t][tl] for lane tl: next step's
            // stay operand, already in the prefetch registers. For j<DEPTH-1
            // pre[j+1] was loaded DEPTH steps ago; for j==DEPTH-1, pre[0]
            // was re-issued at j==0 of this outer iteration for step n+1.
            float bt = pre[(j + 1) % DEPTH].x;

            issue(n + DEPTH, pre[j]);   // prefetch, DP-chain independent

            bool  left = (fla >= fd);         // tie prefers blank (reference)
            float na = left ? fla : fd;
            int   np = (left ? p : pL) + 1;   // total += 1
            if (u == 0) { na = 0.f; np = t * 4096 + 1; }  // alpha[t,0]=0
            a = na; p = np;

            if (u == tl && (unsigned)t < (unsigned)TDIM) {
                lds_la[t] = a + bt;      // la[t] = alpha[t,tl] + blk[t,tl]
                lds_p[t]  = p;
            }
        }
    }

    __syncthreads();
    // Coalesced writeout: la, start, total(+1), plus scalar out[0]=la[T-1].
    for (int t = u; t < TDIM; t += 64) {
        float la = lds_la[t];
        int   pp = lds_p[t];
        out[1 + t]            = la;
        out[1 + TDIM + t]     = (float)(pp >> 12);
        out[1 + 2 * TDIM + t] = (float)((pp & 4095) + 1);
        if (t == TDIM - 1) out[0] = la;
    }
}

extern "C" void kernel_launch(void* const* d_in, const int* in_sizes, int n_in,
                              void* d_out, int out_size, void* d_ws, size_t ws_size,
                              hipStream_t stream)
{
    const float* logits      = (const float*)d_in[0];
    const int*   targets     = (const int*)d_in[1];
    const int*   target_lens = (const int*)d_in[3];
    float* out = (float*)d_out;

    // ws layout: dD[NDIAG*UDIM] float2  (~508 KB)
    float* dD = (float*)d_ws;

    k_rowstats<<<TDIM * UDIM, 256, 0, stream>>>(logits, targets, dD);
    k_dp<<<1, 64, 0, stream>>>((const float2*)dD, target_lens, out);
}

// Round 5
// 336.060 us; speedup vs baseline: 2.7355x; 1.1726x over previous
//
#include <hip/hip_runtime.h>
#include <math.h>

// Problem shape (fixed by the harness): logits [1, T, U, D]
#define TDIM 2000
#define UDIM 32
#define DDIM 4096
#define NDIAG (TDIM + UDIM)   // 2032 anti-diagonals; 2032 = 16 * 127
#define DEPTH 16              // software-pipeline depth for DP loads

// ---------------------------------------------------------------------------
// shfl_up(x,1) via DPP wave_shr:1 (dpp_ctrl 0x138) — pure VALU, ~1-instr
// latency, vs ds_bpermute's ~120+ cy DS round-trip (round-4 lesson: the DP
// recurrence serializes on the cross-lane move, so its latency IS the step
// time). Lane 0 keeps `old` (its own value) — callers override lane 0.
// ---------------------------------------------------------------------------
__device__ __forceinline__ int dpp_up1_i(int x) {
    return __builtin_amdgcn_update_dpp(x, x, 0x138, 0xf, 0xf, false);
}
__device__ __forceinline__ float dpp_up1_f(float x) {
    return __int_as_float(dpp_up1_i(__float_as_int(x)));
}

// ---------------------------------------------------------------------------
// Kernel 1: per (t,u) row of D=4096 logits compute log-softmax at d=0 (blank)
// and d=tgt[u] (emit), writing straight into a DIAGONALIZED INTERLEAVED
// layout so the DP kernel does ONE dwordx2 load per step:
//   dD[n][u].x = blk [n-1-u][u]   (stay path operand at wavefront step n)
//   dD[n][u].y = emit[n-u][u-1]   (emit path operand at wavefront step n)
// Row (t,u) owns slot (t+u+1, u) for .x and slot (t+u+1, u+1) for .y.
// ---------------------------------------------------------------------------
__global__ __launch_bounds__(256) void k_rowstats(
    const float* __restrict__ logits, const int* __restrict__ tgt,
    float* __restrict__ dD)   // float2 array viewed as float*
{
    const int r = blockIdx.x;              // r = t*UDIM + u
    const int t = r >> 5;
    const int u = r & (UDIM - 1);
    const float* row = logits + (size_t)r * DDIM;
    const float4* row4 = reinterpret_cast<const float4*>(row);
    const int tid = threadIdx.x;

    float4 x0 = row4[tid];
    float4 x1 = row4[tid + 256];
    float4 x2 = row4[tid + 512];
    float4 x3 = row4[tid + 768];

    float m = fmaxf(fmaxf(fmaxf(x0.x, x0.y), fmaxf(x0.z, x0.w)),
               fmaxf(fmaxf(fmaxf(x1.x, x1.y), fmaxf(x1.z, x1.w)),
                fmaxf(fmaxf(fmaxf(x2.x, x2.y), fmaxf(x2.z, x2.w)),
                      fmaxf(fmaxf(x3.x, x3.y), fmaxf(x3.z, x3.w)))));
    #pragma unroll
    for (int off = 32; off > 0; off >>= 1)
        m = fmaxf(m, __shfl_xor(m, off));

    __shared__ float redm[4];
    __shared__ float reds[4];
    const int wid = tid >> 6, lane = tid & 63;
    if (lane == 0) redm[wid] = m;
    __syncthreads();
    m = fmaxf(fmaxf(redm[0], redm[1]), fmaxf(redm[2], redm[3]));

    float s = 0.f;
    s += expf(x0.x - m) + expf(x0.y - m) + expf(x0.z - m) + expf(x0.w - m);
    s += expf(x1.x - m) + expf(x1.y - m) + expf(x1.z - m) + expf(x1.w - m);
    s += expf(x2.x - m) + expf(x2.y - m) + expf(x2.z - m) + expf(x2.w - m);
    s += expf(x3.x - m) + expf(x3.y - m) + expf(x3.z - m) + expf(x3.w - m);
    #pragma unroll
    for (int off = 32; off > 0; off >>= 1)
        s += __shfl_xor(s, off);
    if (lane == 0) reds[wid] = s;
    __syncthreads();

    if (tid == 0) {
        float tot = (reds[0] + reds[1]) + (reds[2] + reds[3]);
        float l = logf(tot);
        float b = (x0.x - m) - l;            // log_softmax at d=0 (blank)
        float e = (row[tgt[u]] - m) - l;     // log_softmax at d=tgt[u] (L1-hot)
        const int n = t + u + 1;             // diagonal slot owned by this row
        dD[(n * UDIM + u) * 2] = b;                      // .x of slot (n, u)
        if (u < UDIM - 1)
            dD[(n * UDIM + u + 1) * 2 + 1] = e;          // .y of slot (n, u+1)
    }
}

// ---------------------------------------------------------------------------
// Kernel 2: anti-diagonal wavefront DP, single wave; lane u computes cell
// (t = n-u, u) at step n. Stay path: own prev value (alpha[t-1,u]); emit
// path: lane u-1's prev value via DPP wave_shr:1 — reproducing the
// reference's sequential rounding and ">=" tie-break exactly. (start,total)
// packed into one int (s*4096 + tt, both exact).
//
// Lessons encoded here:
//   r2: no dependent loads in the loop (bt comes from the prefetch ring).
//   r3: no global stores in the loop (they share vmcnt with the prefetch;
//       outputs go to LDS, one coalesced writeout at the end).
//   r4: no ds_bpermute in the recurrence (DS round-trip ~120+ cy serialized
//       per step); DPP is a VALU lane-shift, ~1-instr latency.
// ---------------------------------------------------------------------------
__global__ __launch_bounds__(64) void k_dp(
    const float2* __restrict__ dD, const int* __restrict__ tlenp,
    float* __restrict__ out)
{
    const int u  = (int)threadIdx.x;         // lanes 0..63; u<UDIM meaningful
    const int tl = tlenp[0];                 // = 31

    __shared__ float lds_la[TDIM];
    __shared__ int   lds_p[TDIM];

    const int NMAX = NDIAG * UDIM - 1;

    float a = 0.f;           // alpha of this lane's previous cell (t-1, u)
    int   p = 1;             // packed start*4096 + total of that cell
    float2 pre[DEPTH];

    auto issue = [&](int n, float2& d) {
        int idx = n * UDIM + u;
        idx = min(idx, NMAX);
        d = dD[idx];
    };

    #pragma unroll
    for (int k = 0; k < DEPTH; ++k) issue(k, pre[k]);

    for (int n0 = 0; n0 < NDIAG; n0 += DEPTH) {
        #pragma unroll
        for (int j = 0; j < DEPTH; ++j) {
            const int n = n0 + j;
            const int t = n - u;

            float aL = dpp_up1_f(a);          // lane u-1's alpha (VALU DPP)
            int   pL = dpp_up1_i(p);

            float fla = (t >= 1) ? (a + pre[j].x) : -INFINITY;  // stay (blank)
            float fd  = aL + pre[j].y;                          // emit (label)

            // bt = blkD[(n+1)*UDIM+u] = blk[t][tl] for lane tl: next step's
            // stay operand, already in the prefetch ring. For j<DEPTH-1
            // pre[j+1] was loaded DEPTH steps ago; for j==DEPTH-1, pre[0]
            // was re-issued at j==0 of this outer iteration for step n+1.
            float bt = pre[(j + 1) % DEPTH].x;

            issue(n + DEPTH, pre[j]);   // prefetch, DP-chain independent

            bool  left = (fla >= fd);         // tie prefers blank (reference)
            float na = left ? fla : fd;
            int   np = (left ? p : pL) + 1;   // total += 1
            if (u == 0) { na = 0.f; np = t * 4096 + 1; }  // alpha[t,0]=0
            a = na; p = np;

            if (u == tl && (unsigned)t < (unsigned)TDIM) {
                lds_la[t] = a + bt;      // la[t] = alpha[t,tl] + blk[t,tl]
                lds_p[t]  = p;
            }
        }
    }

    __syncthreads();
    // Coalesced writeout: la, start, total(+1), plus scalar out[0]=la[T-1].
    for (int t = u; t < TDIM; t += 64) {
        float la = lds_la[t];
        int   pp = lds_p[t];
        out[1 + t]            = la;
        out[1 + TDIM + t]     = (float)(pp >> 12);
        out[1 + 2 * TDIM + t] = (float)((pp & 4095) + 1);
        if (t == TDIM - 1) out[0] = la;
    }
}

extern "C" void kernel_launch(void* const* d_in, const int* in_sizes, int n_in,
                              void* d_out, int out_size, void* d_ws, size_t ws_size,
                              hipStream_t stream)
{
    const float* logits      = (const float*)d_in[0];
    const int*   targets     = (const int*)d_in[1];
    const int*   target_lens = (const int*)d_in[3];
    float* out = (float*)d_out;

    // ws layout: dD[NDIAG*UDIM] float2  (~508 KB)
    float* dD = (float*)d_ws;

    k_rowstats<<<TDIM * UDIM, 256, 0, stream>>>(logits, targets, dD);
    k_dp<<<1, 64, 0, stream>>>((const float2*)dD, target_lens, out);
}

// Round 6
// 325.033 us; speedup vs baseline: 2.8283x; 1.0339x over previous
//
#include <hip/hip_runtime.h>
#include <math.h>

// Problem shape (fixed by the harness): logits [1, T, U, D]
#define TDIM 2000
#define UDIM 32
#define DDIM 4096
#define NDIAG (TDIM + UDIM)   // 2032 anti-diagonals; 2032 = 127 * 16
#define DEPTH 16              // software-pipeline depth for DP loads

// ---------------------------------------------------------------------------
// shfl_up(x,1) via DPP wave_shr:1 (dpp_ctrl 0x138) — pure VALU lane shift
// (round-4 lesson: ds_bpermute's DS round-trip serializes the recurrence).
// Lane 0 keeps its own value — callers override lane 0 anyway.
// ---------------------------------------------------------------------------
__device__ __forceinline__ int dpp_up1_i(int x) {
    return __builtin_amdgcn_update_dpp(x, x, 0x138, 0xf, 0xf, false);
}
__device__ __forceinline__ float dpp_up1_f(float x) {
    return __int_as_float(dpp_up1_i(__float_as_int(x)));
}

// ---------------------------------------------------------------------------
// Kernel 1: per (t,u) row of D=4096 logits compute log-softmax at d=0 (blank)
// and d=tgt[u] (emit), writing straight into a DIAGONALIZED INTERLEAVED
// layout so the DP kernel does ONE dwordx2 load per step:
//   dD[n][u].x = blk [n-1-u][u]   (stay path operand at wavefront step n)
//   dD[n][u].y = emit[n-u][u-1]   (emit path operand at wavefront step n)
// Row (t,u) owns slot (t+u+1, u) for .x and slot (t+u+1, u+1) for .y.
// ---------------------------------------------------------------------------
__global__ __launch_bounds__(256) void k_rowstats(
    const float* __restrict__ logits, const int* __restrict__ tgt,
    float* __restrict__ dD)   // float2 array viewed as float*
{
    const int r = blockIdx.x;              // r = t*UDIM + u
    const int t = r >> 5;
    const int u = r & (UDIM - 1);
    const float* row = logits + (size_t)r * DDIM;
    const float4* row4 = reinterpret_cast<const float4*>(row);
    const int tid = threadIdx.x;

    float4 x0 = row4[tid];
    float4 x1 = row4[tid + 256];
    float4 x2 = row4[tid + 512];
    float4 x3 = row4[tid + 768];

    float m = fmaxf(fmaxf(fmaxf(x0.x, x0.y), fmaxf(x0.z, x0.w)),
               fmaxf(fmaxf(fmaxf(x1.x, x1.y), fmaxf(x1.z, x1.w)),
                fmaxf(fmaxf(fmaxf(x2.x, x2.y), fmaxf(x2.z, x2.w)),
                      fmaxf(fmaxf(x3.x, x3.y), fmaxf(x3.z, x3.w)))));
    #pragma unroll
    for (int off = 32; off > 0; off >>= 1)
        m = fmaxf(m, __shfl_xor(m, off));

    __shared__ float redm[4];
    __shared__ float reds[4];
    const int wid = tid >> 6, lane = tid & 63;
    if (lane == 0) redm[wid] = m;
    __syncthreads();
    m = fmaxf(fmaxf(redm[0], redm[1]), fmaxf(redm[2], redm[3]));

    float s = 0.f;
    s += expf(x0.x - m) + expf(x0.y - m) + expf(x0.z - m) + expf(x0.w - m);
    s += expf(x1.x - m) + expf(x1.y - m) + expf(x1.z - m) + expf(x1.w - m);
    s += expf(x2.x - m) + expf(x2.y - m) + expf(x2.z - m) + expf(x2.w - m);
    s += expf(x3.x - m) + expf(x3.y - m) + expf(x3.z - m) + expf(x3.w - m);
    #pragma unroll
    for (int off = 32; off > 0; off >>= 1)
        s += __shfl_xor(s, off);
    if (lane == 0) reds[wid] = s;
    __syncthreads();

    if (tid == 0) {
        float tot = (reds[0] + reds[1]) + (reds[2] + reds[3]);
        float l = logf(tot);
        float b = (x0.x - m) - l;            // log_softmax at d=0 (blank)
        float e = (row[tgt[u]] - m) - l;     // log_softmax at d=tgt[u] (L1-hot)
        const int n = t + u + 1;             // diagonal slot owned by this row
        dD[(n * UDIM + u) * 2] = b;                      // .x of slot (n, u)
        if (u < UDIM - 1)
            dD[(n * UDIM + u + 1) * 2 + 1] = e;          // .y of slot (n, u+1)
    }
}

// ---------------------------------------------------------------------------
// Kernel 2: anti-diagonal wavefront DP, single wave; lane u computes cell
// (t = n-u, u) at step n. Stay path: own prev value (alpha[t-1,u]); emit
// path: lane u-1's prev value via DPP wave_shr:1 — reproducing the
// reference's sequential rounding and ">=" tie-break exactly. (start,total)
// packed into one int (s*4096 + tt, both exact).
//
// Lessons encoded here:
//   r2: no dependent loads in the loop (bt comes from the prefetch ring).
//   r3: no global stores in the loop (outputs go to LDS; one coalesced
//       writeout at the end — stores share vmcnt with the prefetch).
//   r4: no ds_bpermute in the recurrence — DPP lane shift instead.
//   r5: NO ARRAYS, NO LAMBDA in the prefetch ring. Round 2's VGPR_Count=20
//       proved pre[] lived in scratch (rule: runtime-indexed arrays ->
//       local memory); 16 named float2 registers + macro-unrolled body
//       with hard-coded rotation guarantee register residency.
// ---------------------------------------------------------------------------
__global__ __launch_bounds__(64) void k_dp(
    const float2* __restrict__ dD, const int* __restrict__ tlenp,
    float* __restrict__ out)
{
    const int u  = (int)threadIdx.x;         // lanes 0..63; u<UDIM meaningful
    const int tl = tlenp[0];                 // = 31

    __shared__ float lds_la[TDIM];
    __shared__ int   lds_p[TDIM];

    const int NMAX = NDIAG * UDIM - 1;

    float a = 0.f;           // alpha of this lane's previous cell (t-1, u)
    int   p = 1;             // packed start*4096 + total of that cell

    float2 p0,p1,p2,p3,p4,p5,p6,p7,p8,p9,p10,p11,p12,p13,p14,p15;

#define ISSUE(VAR, NN) do {                          \
        int idx_ = (NN) * UDIM + u;                  \
        idx_ = min(idx_, NMAX);                      \
        VAR = dD[idx_];                              \
    } while (0)

    ISSUE(p0,0);  ISSUE(p1,1);  ISSUE(p2,2);   ISSUE(p3,3);
    ISSUE(p4,4);  ISSUE(p5,5);  ISSUE(p6,6);   ISSUE(p7,7);
    ISSUE(p8,8);  ISSUE(p9,9);  ISSUE(p10,10); ISSUE(p11,11);
    ISSUE(p12,12);ISSUE(p13,13);ISSUE(p14,14); ISSUE(p15,15);

// One wavefront step. CUR holds operands for step n = n0+J (loaded 16 steps
// ago); NXT holds step n+1's operands (for J==15, NXT=p0 was re-issued at
// J==0 of this same outer iteration with n0+16 = n+1). bt = NXT.x is
// blk[t][tl] for lane tl — read from register, never a fresh load.
#define STEP(J, CUR, NXT) do {                                        \
        const int n = n0 + (J);                                       \
        const int t = n - u;                                          \
        float aL = dpp_up1_f(a);                                      \
        int   pL = dpp_up1_i(p);                                      \
        float fla = (t >= 1) ? (a + CUR.x) : -INFINITY;               \
        float fd  = aL + CUR.y;                                       \
        float bt  = NXT.x;                                            \
        ISSUE(CUR, n + DEPTH);    /* prefetch, DP-chain independent */ \
        bool  left = (fla >= fd);  /* tie prefers blank (reference) */ \
        float na = left ? fla : fd;                                   \
        int   np = (left ? p : pL) + 1;                               \
        if (u == 0) { na = 0.f; np = (t << 12) + 1; }                 \
        a = na; p = np;                                               \
        if (u == tl && (unsigned)t < (unsigned)TDIM) {                \
            lds_la[t] = a + bt;   /* la = alpha[t,tl] + blk[t,tl] */  \
            lds_p[t]  = p;                                            \
        }                                                             \
    } while (0)

    for (int n0 = 0; n0 < NDIAG; n0 += DEPTH) {
        STEP(0,  p0,  p1);
        STEP(1,  p1,  p2);
        STEP(2,  p2,  p3);
        STEP(3,  p3,  p4);
        STEP(4,  p4,  p5);
        STEP(5,  p5,  p6);
        STEP(6,  p6,  p7);
        STEP(7,  p7,  p8);
        STEP(8,  p8,  p9);
        STEP(9,  p9,  p10);
        STEP(10, p10, p11);
        STEP(11, p11, p12);
        STEP(12, p12, p13);
        STEP(13, p13, p14);
        STEP(14, p14, p15);
        STEP(15, p15, p0);
    }
#undef STEP
#undef ISSUE

    __syncthreads();
    // Coalesced writeout: la, start, total(+1), plus scalar out[0]=la[T-1].
    for (int t = u; t < TDIM; t += 64) {
        float la = lds_la[t];
        int   pp = lds_p[t];
        out[1 + t]            = la;
        out[1 + TDIM + t]     = (float)(pp >> 12);
        out[1 + 2 * TDIM + t] = (float)((pp & 4095) + 1);
        if (t == TDIM - 1) out[0] = la;
    }
}

extern "C" void kernel_launch(void* const* d_in, const int* in_sizes, int n_in,
                              void* d_out, int out_size, void* d_ws, size_t ws_size,
                              hipStream_t stream)
{
    const float* logits      = (const float*)d_in[0];
    const int*   targets     = (const int*)d_in[1];
    const int*   target_lens = (const int*)d_in[3];
    float* out = (float*)d_out;

    // ws layout: dD[NDIAG*UDIM] float2  (~508 KB)
    float* dD = (float*)d_ws;

    k_rowstats<<<TDIM * UDIM, 256, 0, stream>>>(logits, targets, dD);
    k_dp<<<1, 64, 0, stream>>>((const float2*)dD, target_lens, out);
}

// Round 7
// 311.161 us; speedup vs baseline: 2.9544x; 1.0446x over previous
//
#include <hip/hip_runtime.h>
#include <math.h>

// Problem shape (fixed by the harness): logits [1, T, U, D]
#define TDIM 2000
#define UDIM 32
#define DDIM 4096
#define NDIAG 2032            // real anti-diagonals, n in [0, 2031]
#define NSTEP 2048            // padded step count (128 ring-blocks of 16)
#define NPAD  2080            // padded diagonal allocation (loads reach 2063)

// ---------------------------------------------------------------------------
// shfl_up(x,1) via DPP wave_shr:1 — pure VALU lane shift (r4 lesson:
// ds_bpermute's DS round-trip serializes the recurrence). Lane 0 keeps its
// own value — the u==0 override handles it.
// ---------------------------------------------------------------------------
__device__ __forceinline__ int dpp_up1_i(int x) {
    return __builtin_amdgcn_update_dpp(x, x, 0x138, 0xf, 0xf, false);
}
__device__ __forceinline__ float dpp_up1_f(float x) {
    return __int_as_float(dpp_up1_i(__float_as_int(x)));
}

// ---------------------------------------------------------------------------
// Kernel 1: per (t,u) row of D=4096 logits compute log-softmax at d=0 (blank)
// and d=tgt[u] (emit), writing straight into a DIAGONALIZED INTERLEAVED
// layout so the DP kernel does ONE dwordx2 load per step:
//   dD[n][u].x = blk [n-1-u][u]   (stay path operand at wavefront step n)
//   dD[n][u].y = emit[n-u][u-1]   (emit path operand at wavefront step n)
// Row (t,u) owns slot (t+u+1, u) for .x and slot (t+u+1, u+1) for .y.
// ---------------------------------------------------------------------------
__global__ __launch_bounds__(256) void k_rowstats(
    const float* __restrict__ logits, const int* __restrict__ tgt,
    float* __restrict__ dD)   // float2 array viewed as float*
{
    const int r = blockIdx.x;              // r = t*UDIM + u
    const int t = r >> 5;
    const int u = r & (UDIM - 1);
    const float* row = logits + (size_t)r * DDIM;
    const float4* row4 = reinterpret_cast<const float4*>(row);
    const int tid = threadIdx.x;

    float4 x0 = row4[tid];
    float4 x1 = row4[tid + 256];
    float4 x2 = row4[tid + 512];
    float4 x3 = row4[tid + 768];

    float m = fmaxf(fmaxf(fmaxf(x0.x, x0.y), fmaxf(x0.z, x0.w)),
               fmaxf(fmaxf(fmaxf(x1.x, x1.y), fmaxf(x1.z, x1.w)),
                fmaxf(fmaxf(fmaxf(x2.x, x2.y), fmaxf(x2.z, x2.w)),
                      fmaxf(fmaxf(x3.x, x3.y), fmaxf(x3.z, x3.w)))));
    #pragma unroll
    for (int off = 32; off > 0; off >>= 1)
        m = fmaxf(m, __shfl_xor(m, off));

    __shared__ float redm[4];
    __shared__ float reds[4];
    const int wid = tid >> 6, lane = tid & 63;
    if (lane == 0) redm[wid] = m;
    __syncthreads();
    m = fmaxf(fmaxf(redm[0], redm[1]), fmaxf(redm[2], redm[3]));

    float s = 0.f;
    s += expf(x0.x - m) + expf(x0.y - m) + expf(x0.z - m) + expf(x0.w - m);
    s += expf(x1.x - m) + expf(x1.y - m) + expf(x1.z - m) + expf(x1.w - m);
    s += expf(x2.x - m) + expf(x2.y - m) + expf(x2.z - m) + expf(x2.w - m);
    s += expf(x3.x - m) + expf(x3.y - m) + expf(x3.z - m) + expf(x3.w - m);
    #pragma unroll
    for (int off = 32; off > 0; off >>= 1)
        s += __shfl_xor(s, off);
    if (lane == 0) reds[wid] = s;
    __syncthreads();

    if (tid == 0) {
        float tot = (reds[0] + reds[1]) + (reds[2] + reds[3]);
        float l = logf(tot);
        float b = (x0.x - m) - l;            // log_softmax at d=0 (blank)
        float e = (row[tgt[u]] - m) - l;     // log_softmax at d=tgt[u] (L1-hot)
        const int n = t + u + 1;             // diagonal slot owned by this row
        dD[(n * UDIM + u) * 2] = b;                      // .x of slot (n, u)
        if (u < UDIM - 1)
            dD[(n * UDIM + u + 1) * 2 + 1] = e;          // .y of slot (n, u+1)
    }
}

// ---------------------------------------------------------------------------
// Kernel 2: anti-diagonal wavefront DP, single wave; lane u computes cell
// (t = n-u, u) at step n. Stay: own prev value; emit: lane u-1's prev value
// via DPP wave_shr:1 — exact reference rounding and ">=" tie-break.
// (start,total) packed as s*4096+tt (both exact).
//
// Lessons encoded:
//   r2: no dependent loads in the loop (bt from the prefetch ring).
//   r3: no global stores in the loop (LDS outputs; writeout at the end).
//   r4: DPP, not ds_bpermute, for the lane shift.
//   r5: named registers, macro-unrolled ring (no runtime-indexed arrays).
//   r6: (a) L2 warm pre-pass — this wave streams dD into its own XCD's L2
//       first, bounding every ring load at L2-hit latency (~200cy < 14-step
//       slack); (b) branch-free output: ONE unconditional ds_write_b64 per
//       step, address cndmask'd to a trash slot for non-output lanes — no
//       per-step exec-mask writes; (c) t>=1 guard hoisted: only the first
//       64 steps use the guarded STEP variant.
// ---------------------------------------------------------------------------
__global__ __launch_bounds__(64) void k_dp(
    const float2* __restrict__ dD, const int* __restrict__ tlenp,
    float* __restrict__ out)
{
    const int u  = (int)threadIdx.x;
    const int tl = tlenp[0];                 // = 31
    const bool is_tl = (u == tl);

    __shared__ float2 lds_out[NSTEP + 64];   // [0,2048) outputs, [2048+u] trash
    const int trash = NSTEP + u;

    // --- L2 warm pre-pass: pull all of dD (incl. pad) into this XCD's L2 ---
    {
        const float4* w = (const float4*)dD;
        float acc = 0.f;
        #pragma unroll 16
        for (int i = u; i < NPAD * 16; i += 64)   // NPAD*32*8B / 16B
            acc += w[i].x;
        asm volatile("" :: "v"(acc));   // keep the pass alive (no DCE)
    }

    float a = 0.f;           // alpha of this lane's previous cell (t-1, u)
    int   p = 1;             // packed start*4096 + total of that cell

    float2 q0,q1,q2,q3,q4,q5,q6,q7,q8,q9,q10,q11,q12,q13,q14,q15;
    q0  = dD[ 0*UDIM + u];  q1  = dD[ 1*UDIM + u];
    q2  = dD[ 2*UDIM + u];  q3  = dD[ 3*UDIM + u];
    q4  = dD[ 4*UDIM + u];  q5  = dD[ 5*UDIM + u];
    q6  = dD[ 6*UDIM + u];  q7  = dD[ 7*UDIM + u];
    q8  = dD[ 8*UDIM + u];  q9  = dD[ 9*UDIM + u];
    q10 = dD[10*UDIM + u];  q11 = dD[11*UDIM + u];
    q12 = dD[12*UDIM + u];  q13 = dD[13*UDIM + u];
    q14 = dD[14*UDIM + u];  q15 = dD[15*UDIM + u];
    const float2* pref = dD + 16*UDIM + u;   // loads for steps n0+16+J

// One wavefront step. CUR holds step n's operands (loaded 16 steps ago);
// NXT holds step n+1's (for J==15, NXT=q0 was re-issued at J==0 of this
// block for step n+1). bt=NXT.x is blk[t][tl] for lane tl — register read.
// G: compile-time flag for the t>=1 (-INF) guard, needed only for n<64.
#define STEP(J, G, CUR, NXT) do {                                     \
        const int n_ = n0 + (J);                                      \
        const int t_ = n_ - u;                                        \
        float aL_ = dpp_up1_f(a);                                     \
        int   pL_ = dpp_up1_i(p);                                     \
        float fla_ = a + CUR.x;                                       \
        if (G) fla_ = (t_ >= 1) ? fla_ : -INFINITY;                   \
        float fd_ = aL_ + CUR.y;                                      \
        float bt_ = NXT.x;                                            \
        CUR = pref[(J) * UDIM];   /* prefetch, imm offset J*256 */    \
        bool  left_ = (fla_ >= fd_);  /* tie prefers blank */         \
        float na_ = left_ ? fla_ : fd_;                               \
        int   np_ = (left_ ? p : pL_) + 1;                            \
        if (u == 0) { na_ = 0.f; np_ = (n_ << 12) + 1; }              \
        a = na_; p = np_;                                             \
        int slot_ = (is_tl && (unsigned)t_ < (unsigned)TDIM) ? t_     \
                                                             : trash; \
        lds_out[slot_] = make_float2(a + bt_, __int_as_float(p));     \
    } while (0)

#define BLOCK16(G) do {                                               \
        STEP(0,G,q0,q1);   STEP(1,G,q1,q2);   STEP(2,G,q2,q3);        \
        STEP(3,G,q3,q4);   STEP(4,G,q4,q5);   STEP(5,G,q5,q6);        \
        STEP(6,G,q6,q7);   STEP(7,G,q7,q8);   STEP(8,G,q8,q9);        \
        STEP(9,G,q9,q10);  STEP(10,G,q10,q11);STEP(11,G,q11,q12);     \
        STEP(12,G,q12,q13);STEP(13,G,q13,q14);STEP(14,G,q14,q15);     \
        STEP(15,G,q15,q0);                                            \
        pref += 16 * UDIM;                                            \
    } while (0)

    int n0 = 0;
    BLOCK16(1); n0 += 16;     // steps 0..63 need the t>=1 guard
    BLOCK16(1); n0 += 16;
    BLOCK16(1); n0 += 16;
    BLOCK16(1); n0 += 16;
    for (; n0 < NSTEP; n0 += 16)   // 124 slim blocks, steps 64..2047
        BLOCK16(0);

#undef STEP
#undef BLOCK16

    __syncthreads();
    // Coalesced writeout: la, start, total(+1), plus scalar out[0]=la[T-1].
    for (int t = u; t < TDIM; t += 64) {
        float2 v = lds_out[t];
        int pp = __float_as_int(v.y);
        out[1 + t]            = v.x;
        out[1 + TDIM + t]     = (float)(pp >> 12);
        out[1 + 2 * TDIM + t] = (float)((pp & 4095) + 1);
        if (t == TDIM - 1) out[0] = v.x;
    }
}

extern "C" void kernel_launch(void* const* d_in, const int* in_sizes, int n_in,
                              void* d_out, int out_size, void* d_ws, size_t ws_size,
                              hipStream_t stream)
{
    const float* logits      = (const float*)d_in[0];
    const int*   targets     = (const int*)d_in[1];
    const int*   target_lens = (const int*)d_in[3];
    float* out = (float*)d_out;

    // ws layout: dD[NPAD*UDIM] float2 (~533 KB; pad diagonals never written —
    // poison-finite, provably isolated from stored outputs)
    float* dD = (float*)d_ws;

    k_rowstats<<<TDIM * UDIM, 256, 0, stream>>>(logits, targets, dD);
    k_dp<<<1, 64, 0, stream>>>((const float2*)dD, target_lens, out);
}